// Round 3
// baseline (721.758 us; speedup 1.0000x reference)
//
#include <hip/hip_runtime.h>
#include <hip/hip_bf16.h>
#include <stdint.h>

#define N_TOK 2048
#define DM    2048
#define NEXP  64
#define TOPK  4
#define HEXP  512
#define CAPC  512
#define NSH   2
#define HSH   2048
#define RTB   8

typedef __attribute__((ext_vector_type(8))) short short8;
typedef __attribute__((ext_vector_type(4))) short short4v;
typedef __attribute__((ext_vector_type(4))) float f32x4;
typedef __attribute__((ext_vector_type(4))) float f4;

// Raw barrier: LDS-write visibility only. NEVER drains vmcnt -> global loads
// stay in flight across phases (this is the whole point vs __syncthreads()).
#define LGKM_BAR() asm volatile("s_waitcnt lgkmcnt(0)\n\ts_barrier" ::: "memory")

static __device__ __forceinline__ unsigned short f2bf(float f) {
  union { float f; unsigned u; } v; v.f = f;
  unsigned r = v.u + 0x7FFFu + ((v.u >> 16) & 1u);   // RNE
  return (unsigned short)(r >> 16);
}

// ---------------------------------------------------------------- convert x
__global__ __launch_bounds__(256) void k_convert(const float* __restrict__ x,
                                                 unsigned short* __restrict__ xb) {
  int i = (blockIdx.x * 256 + threadIdx.x) * 8;
  f4 a = *(const f4*)(x + i);
  f4 b = *(const f4*)(x + i + 4);
  short8 o;
  o[0]=f2bf(a[0]); o[1]=f2bf(a[1]); o[2]=f2bf(a[2]); o[3]=f2bf(a[3]);
  o[4]=f2bf(b[0]); o[5]=f2bf(b[1]); o[6]=f2bf(b[2]); o[7]=f2bf(b[3]);
  *(short8*)(xb + i) = o;
}

// ---------------------------------------------------------------- router
#define ARGMAX_ROUND(S,I)                                            \
  { float bv = v; int bi = lane;                                     \
    _Pragma("unroll")                                                \
    for (int o = 32; o; o >>= 1) {                                   \
      float ov = __shfl_xor(bv, o); int oi = __shfl_xor(bi, o);      \
      if (ov > bv || (ov == bv && oi < bi)) { bv = ov; bi = oi; }    \
    }                                                                \
    S = bv; I = bi; if (lane == bi) v = -1.f; }

__global__ __launch_bounds__(256) void k_router(const float* __restrict__ x,
    const float* __restrict__ Wr, const float* __restrict__ bias,
    int* __restrict__ cnt, int* __restrict__ lists, float* __restrict__ wlist) {
  __shared__ float part[4][RTB][64];
  __shared__ float logits[RTB][64];
  int t = threadIdx.x;
  int e = t & 63, sl = t >> 6;
  int tok0 = blockIdx.x * RTB;
  const float* xp = x + (size_t)tok0 * DM;
  float acc[RTB];
#pragma unroll
  for (int i = 0; i < RTB; ++i) acc[i] = 0.f;
  for (int d = sl * 512; d < sl * 512 + 512; ++d) {
    float w = Wr[(size_t)d * NEXP + e];
#pragma unroll
    for (int i = 0; i < RTB; ++i) acc[i] += xp[(size_t)i * DM + d] * w;
  }
#pragma unroll
  for (int i = 0; i < RTB; ++i) part[sl][i][e] = acc[i];
  __syncthreads();
  for (int i = sl; i < RTB; i += 4)
    logits[i][e] = part[0][i][e] + part[1][i][e] + part[2][i][e] + part[3][i][e] + bias[e];
  __syncthreads();
  int lane = t & 63, wv = t >> 6;
  for (int i = wv * 2; i < wv * 2 + 2; ++i) {
    float lg = logits[i][lane];
    float m = lg;
#pragma unroll
    for (int o = 32; o; o >>= 1) m = fmaxf(m, __shfl_xor(m, o));
    float p = expf(lg - m);
    float sm = p;
#pragma unroll
    for (int o = 32; o; o >>= 1) sm += __shfl_xor(sm, o);
    float v = p / sm;
    float s0, s1, s2, s3; int i0, i1, i2, i3;
    ARGMAX_ROUND(s0, i0)
    ARGMAX_ROUND(s1, i1)
    ARGMAX_ROUND(s2, i2)
    ARGMAX_ROUND(s3, i3)
    float tot = s0 + s1 + s2 + s3;
    if (lane < TOPK) {
      float myw = (lane == 0 ? s0 : lane == 1 ? s1 : lane == 2 ? s2 : s3) / tot;
      int   mye = (lane == 0 ? i0 : lane == 1 ? i1 : lane == 2 ? i2 : i3);
      int pos = atomicAdd(&cnt[mye], 1);
      if (pos < CAPC) {
        lists[mye * CAPC + pos] = tok0 + i;
        wlist[mye * CAPC + pos] = myw;
      }
    }
  }
}

// ---------------------------------------------------------------- offsets
__global__ void k_offs(const int* __restrict__ cnt, int* __restrict__ offs) {
  int l = threadIdx.x;            // 64 threads
  int c = min(cnt[l], CAPC);
  int sum = c;
#pragma unroll
  for (int o = 1; o < 64; o <<= 1) {
    int ov = __shfl_up(sum, o);
    if (l >= o) sum += ov;
  }
  offs[l + 1] = sum;
  if (l == 0) offs[0] = 0;
}

// ---------------------------------------------------------------- GEMM pieces
// LDS tiles: A [128][64] bf16 (row-major, 128B rows), B [64 n][64 k] bf16.
// XOR swizzle: byte ^= (row&7)<<4  (both write and read sides).

template<bool GATHER>
static __device__ __forceinline__ void loadA(const unsigned short* __restrict__ src,
    int lda, int m0, int Mvalid, const int* __restrict__ gl, int k0, short8 (&r)[4]) {
  int tid = threadIdx.x;
#pragma unroll
  for (int p = 0; p < 4; ++p) {
    int idx = p * 256 + tid;
    int row = idx >> 3;
    int ko  = (idx & 7) * 8;
    int grow = m0 + row;
    if (grow < Mvalid) {
      int srow = GATHER ? gl[grow] : grow;
      r[p] = *(const short8*)(src + (size_t)srow * lda + k0 + ko);
    } else {
#pragma unroll
      for (int j = 0; j < 8; ++j) r[p][j] = 0;
    }
  }
}

static __device__ __forceinline__ void writeA(const short8 (&r)[4], unsigned short* lA) {
  int tid = threadIdx.x;
#pragma unroll
  for (int p = 0; p < 4; ++p) {
    int idx = p * 256 + tid;
    int row = idx >> 3;
    int ko  = (idx & 7) * 8;
    int byte = row * 128 + ko * 2;
    byte ^= (row & 7) << 4;
    *(short8*)((char*)lA + byte) = r[p];
  }
}

static __device__ __forceinline__ void loadB(const float* __restrict__ B, int ldb,
    int k0, int n0, f4 (&r)[4]) {
  int tid = threadIdx.x;
  int kb = tid >> 4;               // k block of 4
  int nb = tid & 15;               // n block of 4
  const float* p = B + (size_t)(k0 + kb * 4) * ldb + n0 + nb * 4;
#pragma unroll
  for (int q = 0; q < 4; ++q) r[q] = *(const f4*)(p + (size_t)q * ldb);
}

static __device__ __forceinline__ void writeB(const f4 (&r)[4], unsigned short* lB) {
  int tid = threadIdx.x;
  int kb = tid >> 4;
  int nb = tid & 15;
#pragma unroll
  for (int c = 0; c < 4; ++c) {
    short4v vv;
    vv[0] = (short)f2bf(r[0][c]); vv[1] = (short)f2bf(r[1][c]);
    vv[2] = (short)f2bf(r[2][c]); vv[3] = (short)f2bf(r[3][c]);
    int n = nb * 4 + c;
    int byte = n * 128 + kb * 8;
    byte ^= (n & 7) << 4;
    *(short4v*)((char*)lB + byte) = vv;
  }
}

static __device__ __forceinline__ short8 frag_ld(const unsigned short* lds, int row, int kElem) {
  int byte = row * 128 + kElem * 2;
  byte ^= (row & 7) << 4;
  return *(const short8*)((const char*)lds + byte);
}

static __device__ __forceinline__ void mma1(const unsigned short* lA, const unsigned short* lB,
    f32x4 (&acc)[4][2], int wm, int wn, int lane) {
  int r16 = lane & 15;
  int kg  = (lane >> 4) * 8;
#pragma unroll
  for (int kk = 0; kk < 2; ++kk) {
    int kb = kk * 32 + kg;
    short8 a[4], b[2];
#pragma unroll
    for (int mf = 0; mf < 4; ++mf) a[mf] = frag_ld(lA, wm + mf * 16 + r16, kb);
#pragma unroll
    for (int nf = 0; nf < 2; ++nf) b[nf] = frag_ld(lB, wn + nf * 16 + r16, kb);
#pragma unroll
    for (int mf = 0; mf < 4; ++mf)
#pragma unroll
      for (int nf = 0; nf < 2; ++nf)
        acc[mf][nf] = __builtin_amdgcn_mfma_f32_16x16x32_bf16(a[mf], b[nf], acc[mf][nf], 0, 0, 0);
  }
}

static __device__ __forceinline__ void mma2(const unsigned short* lA,
    const unsigned short* lBg, const unsigned short* lBu,
    f32x4 (&accg)[4][2], f32x4 (&accu)[4][2], int wm, int wn, int lane) {
  int r16 = lane & 15;
  int kg  = (lane >> 4) * 8;
#pragma unroll
  for (int kk = 0; kk < 2; ++kk) {
    int kb = kk * 32 + kg;
    short8 a[4], bg[2], bu[2];
#pragma unroll
    for (int mf = 0; mf < 4; ++mf) a[mf] = frag_ld(lA, wm + mf * 16 + r16, kb);
#pragma unroll
    for (int nf = 0; nf < 2; ++nf) {
      bg[nf] = frag_ld(lBg, wn + nf * 16 + r16, kb);
      bu[nf] = frag_ld(lBu, wn + nf * 16 + r16, kb);
    }
#pragma unroll
    for (int mf = 0; mf < 4; ++mf)
#pragma unroll
      for (int nf = 0; nf < 2; ++nf) {
        accg[mf][nf] = __builtin_amdgcn_mfma_f32_16x16x32_bf16(a[mf], bg[nf], accg[mf][nf], 0, 0, 0);
        accu[mf][nf] = __builtin_amdgcn_mfma_f32_16x16x32_bf16(a[mf], bu[nf], accu[mf][nf], 0, 0, 0);
      }
  }
}

static __device__ __forceinline__ float silu_mul(float g, float u) {
  return g / (1.f + expf(-g)) * u;
}

// ---------------------------------------------------------------- expert gate+up
__global__ __launch_bounds__(256) void k_expert_gateup(const unsigned short* __restrict__ xbf,
    const float* __restrict__ Wg, const float* __restrict__ Wu,
    const int* __restrict__ cnt, const int* __restrict__ offs,
    const int* __restrict__ lists, unsigned short* __restrict__ hws) {
  int e = blockIdx.y;
  int ne = min(cnt[e], CAPC);
  if (ne == 0) return;
  int n0 = blockIdx.x * 64;
  const float* Bg = Wg + (size_t)e * DM * HEXP;
  const float* Bu = Wu + (size_t)e * DM * HEXP;
  const int* lst = lists + e * CAPC;
  int base = offs[e];
  __shared__ unsigned short lA[2][128 * 64];
  __shared__ unsigned short lBg[2][64 * 64];
  __shared__ unsigned short lBu[2][64 * 64];
  int lane = threadIdx.x & 63, wv = threadIdx.x >> 6;
  int wm = (wv >> 1) * 64, wn = (wv & 1) * 32;
  for (int m0 = 0; m0 < ne; m0 += 128) {
    f32x4 accg[4][2] = {};
    f32x4 accu[4][2] = {};
    short8 ra[4]; f4 rg[4], ru[4];
    loadA<true>(xbf, DM, m0, ne, lst, 0, ra);
    loadB(Bg, HEXP, 0, n0, rg);
    loadB(Bu, HEXP, 0, n0, ru);
    writeA(ra, lA[0]); writeB(rg, lBg[0]); writeB(ru, lBu[0]);
    loadA<true>(xbf, DM, m0, ne, lst, 64, ra);
    loadB(Bg, HEXP, 64, n0, rg);
    loadB(Bu, HEXP, 64, n0, ru);
    LGKM_BAR();
#pragma unroll 1
    for (int k0 = 0; k0 < DM; k0 += 128) {
      mma2(lA[0], lBg[0], lBu[0], accg, accu, wm, wn, lane);
      writeA(ra, lA[1]); writeB(rg, lBg[1]); writeB(ru, lBu[1]);
      if (k0 + 128 < DM) {
        loadA<true>(xbf, DM, m0, ne, lst, k0 + 128, ra);
        loadB(Bg, HEXP, k0 + 128, n0, rg);
        loadB(Bu, HEXP, k0 + 128, n0, ru);
      }
      LGKM_BAR();
      mma2(lA[1], lBg[1], lBu[1], accg, accu, wm, wn, lane);
      if (k0 + 128 < DM) {
        writeA(ra, lA[0]); writeB(rg, lBg[0]); writeB(ru, lBu[0]);
        if (k0 + 192 < DM) {
          loadA<true>(xbf, DM, m0, ne, lst, k0 + 192, ra);
          loadB(Bg, HEXP, k0 + 192, n0, rg);
          loadB(Bu, HEXP, k0 + 192, n0, ru);
        }
      }
      LGKM_BAR();
    }
#pragma unroll
    for (int mf = 0; mf < 4; ++mf)
#pragma unroll
      for (int r = 0; r < 4; ++r) {
        int rl = m0 + wm + mf * 16 + (lane >> 4) * 4 + r;
        if (rl < ne) {
#pragma unroll
          for (int nf = 0; nf < 2; ++nf) {
            int col = n0 + wn + nf * 16 + (lane & 15);
            float h = silu_mul(accg[mf][nf][r], accu[mf][nf][r]);
            hws[(size_t)(base + rl) * HEXP + col] = f2bf(h);
          }
        }
      }
  }
}

// ---------------------------------------------------------------- shared gate+up
__global__ __launch_bounds__(256) void k_shared_gateup(const unsigned short* __restrict__ xbf,
    const float* __restrict__ Sg, const float* __restrict__ Su,
    unsigned short* __restrict__ hs) {
  int n0 = blockIdx.x * 64;
  int m0 = blockIdx.y * 128;
  int s  = blockIdx.z;
  const float* Bg = Sg + (size_t)s * DM * HSH;
  const float* Bu = Su + (size_t)s * DM * HSH;
  __shared__ unsigned short lA[2][128 * 64];
  __shared__ unsigned short lBg[2][64 * 64];
  __shared__ unsigned short lBu[2][64 * 64];
  int lane = threadIdx.x & 63, wv = threadIdx.x >> 6;
  int wm = (wv >> 1) * 64, wn = (wv & 1) * 32;
  f32x4 accg[4][2] = {};
  f32x4 accu[4][2] = {};
  short8 ra[4]; f4 rg[4], ru[4];
  loadA<false>(xbf, DM, m0, N_TOK, nullptr, 0, ra);
  loadB(Bg, HSH, 0, n0, rg);
  loadB(Bu, HSH, 0, n0, ru);
  writeA(ra, lA[0]); writeB(rg, lBg[0]); writeB(ru, lBu[0]);
  loadA<false>(xbf, DM, m0, N_TOK, nullptr, 64, ra);
  loadB(Bg, HSH, 64, n0, rg);
  loadB(Bu, HSH, 64, n0, ru);
  LGKM_BAR();
#pragma unroll 1
  for (int k0 = 0; k0 < DM; k0 += 128) {
    mma2(lA[0], lBg[0], lBu[0], accg, accu, wm, wn, lane);
    writeA(ra, lA[1]); writeB(rg, lBg[1]); writeB(ru, lBu[1]);
    if (k0 + 128 < DM) {
      loadA<false>(xbf, DM, m0, N_TOK, nullptr, k0 + 128, ra);
      loadB(Bg, HSH, k0 + 128, n0, rg);
      loadB(Bu, HSH, k0 + 128, n0, ru);
    }
    LGKM_BAR();
    mma2(lA[1], lBg[1], lBu[1], accg, accu, wm, wn, lane);
    if (k0 + 128 < DM) {
      writeA(ra, lA[0]); writeB(rg, lBg[0]); writeB(ru, lBu[0]);
      if (k0 + 192 < DM) {
        loadA<false>(xbf, DM, m0, N_TOK, nullptr, k0 + 192, ra);
        loadB(Bg, HSH, k0 + 192, n0, rg);
        loadB(Bu, HSH, k0 + 192, n0, ru);
      }
    }
    LGKM_BAR();
  }
#pragma unroll
  for (int mf = 0; mf < 4; ++mf)
#pragma unroll
    for (int nf = 0; nf < 2; ++nf)
#pragma unroll
      for (int r = 0; r < 4; ++r) {
        int row = m0 + wm + mf * 16 + (lane >> 4) * 4 + r;
        int col = n0 + wn + nf * 16 + (lane & 15);
        float h = silu_mul(accg[mf][nf][r], accu[mf][nf][r]);
        hs[(size_t)row * (NSH * HSH) + s * HSH + col] = f2bf(h);
      }
}

// ---------------------------------------------------------------- shared down (writes out)
__global__ __launch_bounds__(256) void k_shared_down(const unsigned short* __restrict__ hs,
    const float* __restrict__ Sd, float* __restrict__ out) {
  int n0 = blockIdx.x * 64;
  int m0 = blockIdx.y * 128;
  __shared__ unsigned short lA[2][128 * 64];
  __shared__ unsigned short lB[2][64 * 64];
  int lane = threadIdx.x & 63, wv = threadIdx.x >> 6;
  int wm = (wv >> 1) * 64, wn = (wv & 1) * 32;
  f32x4 acc[4][2] = {};
  short8 ra[4]; f4 rb[4];
  loadA<false>(hs, NSH * HSH, m0, N_TOK, nullptr, 0, ra);
  loadB(Sd, DM, 0, n0, rb);
  writeA(ra, lA[0]); writeB(rb, lB[0]);
  loadA<false>(hs, NSH * HSH, m0, N_TOK, nullptr, 64, ra);
  loadB(Sd, DM, 64, n0, rb);
  LGKM_BAR();
#pragma unroll 1
  for (int k0 = 0; k0 < NSH * HSH; k0 += 128) {
    mma1(lA[0], lB[0], acc, wm, wn, lane);
    writeA(ra, lA[1]); writeB(rb, lB[1]);
    if (k0 + 128 < NSH * HSH) {
      loadA<false>(hs, NSH * HSH, m0, N_TOK, nullptr, k0 + 128, ra);
      loadB(Sd, DM, k0 + 128, n0, rb);
    }
    LGKM_BAR();
    mma1(lA[1], lB[1], acc, wm, wn, lane);
    if (k0 + 128 < NSH * HSH) {
      writeA(ra, lA[0]); writeB(rb, lB[0]);
      if (k0 + 192 < NSH * HSH) {
        loadA<false>(hs, NSH * HSH, m0, N_TOK, nullptr, k0 + 192, ra);
        loadB(Sd, DM, k0 + 192, n0, rb);
      }
    }
    LGKM_BAR();
  }
#pragma unroll
  for (int mf = 0; mf < 4; ++mf)
#pragma unroll
    for (int nf = 0; nf < 2; ++nf)
#pragma unroll
      for (int r = 0; r < 4; ++r) {
        int row = m0 + wm + mf * 16 + (lane >> 4) * 4 + r;
        int col = n0 + wn + nf * 16 + (lane & 15);
        out[(size_t)row * DM + col] = acc[mf][nf][r];
      }
}

// ---------------------------------------------------------------- expert down (atomic add)
__global__ __launch_bounds__(256) void k_expert_down(const unsigned short* __restrict__ hws,
    const float* __restrict__ Wd, const int* __restrict__ cnt, const int* __restrict__ offs,
    const int* __restrict__ lists, const float* __restrict__ wlist,
    float* __restrict__ out) {
  int e = blockIdx.y;
  int ne = min(cnt[e], CAPC);
  if (ne == 0) return;
  int n0 = blockIdx.x * 64;
  const float* B = Wd + (size_t)e * HEXP * DM;
  const unsigned short* A = hws + (size_t)offs[e] * HEXP;
  __shared__ unsigned short lA[2][128 * 64];
  __shared__ unsigned short lB[2][64 * 64];
  int lane = threadIdx.x & 63, wv = threadIdx.x >> 6;
  int wm = (wv >> 1) * 64, wn = (wv & 1) * 32;
  for (int m0 = 0; m0 < ne; m0 += 128) {
    f32x4 acc[4][2] = {};
    short8 ra[4]; f4 rb[4];
    loadA<false>(A, HEXP, m0, ne, nullptr, 0, ra);
    loadB(B, DM, 0, n0, rb);
    writeA(ra, lA[0]); writeB(rb, lB[0]);
    loadA<false>(A, HEXP, m0, ne, nullptr, 64, ra);
    loadB(B, DM, 64, n0, rb);
    LGKM_BAR();
#pragma unroll 1
    for (int k0 = 0; k0 < HEXP; k0 += 128) {
      mma1(lA[0], lB[0], acc, wm, wn, lane);
      writeA(ra, lA[1]); writeB(rb, lB[1]);
      if (k0 + 128 < HEXP) {
        loadA<false>(A, HEXP, m0, ne, nullptr, k0 + 128, ra);
        loadB(B, DM, k0 + 128, n0, rb);
      }
      LGKM_BAR();
      mma1(lA[1], lB[1], acc, wm, wn, lane);
      if (k0 + 128 < HEXP) {
        writeA(ra, lA[0]); writeB(rb, lB[0]);
        if (k0 + 192 < HEXP) {
          loadA<false>(A, HEXP, m0, ne, nullptr, k0 + 192, ra);
          loadB(B, DM, k0 + 192, n0, rb);
        }
      }
      LGKM_BAR();
    }
#pragma unroll
    for (int mf = 0; mf < 4; ++mf)
#pragma unroll
      for (int r = 0; r < 4; ++r) {
        int rl = m0 + wm + mf * 16 + (lane >> 4) * 4 + r;
        if (rl < ne) {
          int tok  = lists[e * CAPC + rl];
          float w  = wlist[e * CAPC + rl];
#pragma unroll
          for (int nf = 0; nf < 2; ++nf) {
            int col = n0 + wn + nf * 16 + (lane & 15);
            atomicAdd(out + (size_t)tok * DM + col, acc[mf][nf][r] * w);
          }
        }
      }
  }
}

// ---------------------------------------------------------------- launch
extern "C" void kernel_launch(void* const* d_in, const int* in_sizes, int n_in,
                              void* d_out, int out_size, void* d_ws, size_t ws_size,
                              hipStream_t stream) {
  const float* x    = (const float*)d_in[0];
  const float* Wr   = (const float*)d_in[1];
  const float* bias = (const float*)d_in[2];
  const float* Wg   = (const float*)d_in[3];
  const float* Wu   = (const float*)d_in[4];
  const float* Wd   = (const float*)d_in[5];
  const float* Sg   = (const float*)d_in[6];
  const float* Su   = (const float*)d_in[7];
  const float* Sd   = (const float*)d_in[8];
  float* out = (float*)d_out;
  char* ws = (char*)d_ws;

  const size_t off_cnt   = 0;
  const size_t off_offs  = 256;
  const size_t off_lists = 1024;
  const size_t off_wlist = off_lists + (size_t)NEXP * CAPC * 4;
  const size_t off_xbf   = off_wlist + (size_t)NEXP * CAPC * 4;
  const size_t off_hs    = off_xbf + (size_t)N_TOK * DM * 2;
  const size_t off_h     = off_hs + (size_t)N_TOK * NSH * HSH * 2;
  const size_t req       = off_h + (size_t)N_TOK * TOPK * HEXP * 2;
  if (ws_size < req) return;   // loud failure, no corruption

  int* cnt            = (int*)(ws + off_cnt);
  int* offs           = (int*)(ws + off_offs);
  int* lists          = (int*)(ws + off_lists);
  float* wlist        = (float*)(ws + off_wlist);
  unsigned short* xbf = (unsigned short*)(ws + off_xbf);
  unsigned short* hs  = (unsigned short*)(ws + off_hs);
  unsigned short* hws = (unsigned short*)(ws + off_h);

  hipMemsetAsync(cnt, 0, NEXP * sizeof(int), stream);
  k_convert<<<(N_TOK * DM) / (256 * 8), 256, 0, stream>>>(x, xbf);
  k_router<<<N_TOK / RTB, 256, 0, stream>>>(x, Wr, bias, cnt, lists, wlist);
  k_offs<<<1, 64, 0, stream>>>(cnt, offs);
  k_expert_gateup<<<dim3(HEXP / 64, NEXP), 256, 0, stream>>>(xbf, Wg, Wu, cnt, offs, lists, hws);
  k_shared_gateup<<<dim3(HSH / 64, N_TOK / 128, NSH), 256, 0, stream>>>(xbf, Sg, Su, hs);
  k_shared_down<<<dim3(DM / 64, N_TOK / 128), 256, 0, stream>>>(hs, Sd, out);
  k_expert_down<<<dim3(DM / 64, NEXP), 256, 0, stream>>>(hws, Wd, cnt, offs, lists, wlist, out);
}

// Round 4
// 670.863 us; speedup vs baseline: 1.0759x; 1.0759x over previous
//
#include <hip/hip_runtime.h>
#include <hip/hip_bf16.h>
#include <stdint.h>

#define N_TOK 2048
#define DM    2048
#define NEXP  64
#define TOPK  4
#define HEXP  512
#define CAPC  512
#define NSH   2
#define HSH   2048
#define RTB   8

typedef __attribute__((ext_vector_type(8))) short short8;
typedef __attribute__((ext_vector_type(4))) float f32x4;
typedef __attribute__((ext_vector_type(4))) float f4;

// Direct global->LDS DMA, 16B per lane. LDS dest is wave-uniform base + lane*16.
#define GLDS16(g, l) __builtin_amdgcn_global_load_lds(                     \
    (const __attribute__((address_space(1))) void*)(g),                    \
    (__attribute__((address_space(3))) void*)(l), 16, 0, 0)

static __device__ __forceinline__ unsigned short f2bf(float f) {
  union { float f; unsigned u; } v; v.f = f;
  unsigned r = v.u + 0x7FFFu + ((v.u >> 16) & 1u);   // RNE
  return (unsigned short)(r >> 16);
}

// ---------------------------------------------------------------- convert x
__global__ __launch_bounds__(256) void k_convert(const float* __restrict__ x,
                                                 unsigned short* __restrict__ xb) {
  int i = (blockIdx.x * 256 + threadIdx.x) * 8;
  f4 a = *(const f4*)(x + i);
  f4 b = *(const f4*)(x + i + 4);
  short8 o;
  o[0]=f2bf(a[0]); o[1]=f2bf(a[1]); o[2]=f2bf(a[2]); o[3]=f2bf(a[3]);
  o[4]=f2bf(b[0]); o[5]=f2bf(b[1]); o[6]=f2bf(b[2]); o[7]=f2bf(b[3]);
  *(short8*)(xb + i) = o;
}

// ---------------------------------------------------------------- router
#define ARGMAX_ROUND(S,I)                                            \
  { float bv = v; int bi = lane;                                     \
    _Pragma("unroll")                                                \
    for (int o = 32; o; o >>= 1) {                                   \
      float ov = __shfl_xor(bv, o); int oi = __shfl_xor(bi, o);      \
      if (ov > bv || (ov == bv && oi < bi)) { bv = ov; bi = oi; }    \
    }                                                                \
    S = bv; I = bi; if (lane == bi) v = -1.f; }

__global__ __launch_bounds__(256) void k_router(const float* __restrict__ x,
    const float* __restrict__ Wr, const float* __restrict__ bias,
    int* __restrict__ cnt, int* __restrict__ lists, float* __restrict__ wlist) {
  __shared__ float part[4][RTB][64];
  __shared__ float logits[RTB][64];
  int t = threadIdx.x;
  int e = t & 63, sl = t >> 6;
  int tok0 = blockIdx.x * RTB;
  const float* xp = x + (size_t)tok0 * DM;
  float acc[RTB];
#pragma unroll
  for (int i = 0; i < RTB; ++i) acc[i] = 0.f;
  for (int d = sl * 512; d < sl * 512 + 512; ++d) {
    float w = Wr[(size_t)d * NEXP + e];
#pragma unroll
    for (int i = 0; i < RTB; ++i) acc[i] += xp[(size_t)i * DM + d] * w;
  }
#pragma unroll
  for (int i = 0; i < RTB; ++i) part[sl][i][e] = acc[i];
  __syncthreads();
  for (int i = sl; i < RTB; i += 4)
    logits[i][e] = part[0][i][e] + part[1][i][e] + part[2][i][e] + part[3][i][e] + bias[e];
  __syncthreads();
  int lane = t & 63, wv = t >> 6;
  for (int i = wv * 2; i < wv * 2 + 2; ++i) {
    float lg = logits[i][lane];
    float m = lg;
#pragma unroll
    for (int o = 32; o; o >>= 1) m = fmaxf(m, __shfl_xor(m, o));
    float p = expf(lg - m);
    float sm = p;
#pragma unroll
    for (int o = 32; o; o >>= 1) sm += __shfl_xor(sm, o);
    float v = p / sm;
    float s0, s1, s2, s3; int i0, i1, i2, i3;
    ARGMAX_ROUND(s0, i0)
    ARGMAX_ROUND(s1, i1)
    ARGMAX_ROUND(s2, i2)
    ARGMAX_ROUND(s3, i3)
    float tot = s0 + s1 + s2 + s3;
    if (lane < TOPK) {
      float myw = (lane == 0 ? s0 : lane == 1 ? s1 : lane == 2 ? s2 : s3) / tot;
      int   mye = (lane == 0 ? i0 : lane == 1 ? i1 : lane == 2 ? i2 : i3);
      int pos = atomicAdd(&cnt[mye], 1);
      if (pos < CAPC) {
        lists[mye * CAPC + pos] = tok0 + i;
        wlist[mye * CAPC + pos] = myw;
      }
    }
  }
}

// ---------------------------------------------------------------- offsets
__global__ void k_offs(const int* __restrict__ cnt, int* __restrict__ offs) {
  int l = threadIdx.x;            // 64 threads
  int c = min(cnt[l], CAPC);
  int sum = c;
#pragma unroll
  for (int o = 1; o < 64; o <<= 1) {
    int ov = __shfl_up(sum, o);
    if (l >= o) sum += ov;
  }
  offs[l + 1] = sum;
  if (l == 0) offs[0] = 0;
}

// ---------------------------------------------------------------- GEMM pieces
// A LDS: [128 rows][64 k] bf16 (128B rows), XOR-swizzled: the DMA writes
// linearly; the SOURCE chunk is permuted c^=(row&7) so the swizzled read
// (byte ^= (row&7)<<4) recovers the true data (both-sides rule).
// B LDS: [64 k][64 n] fp32, linear (true layout), read along k as b32.

static __device__ __forceinline__ short8 frag_ldA(const unsigned short* lds, int row, int kElem) {
  int byte = row * 128 + kElem * 2;
  byte ^= (row & 7) << 4;
  return *(const short8*)((const char*)lds + byte);
}

static __device__ __forceinline__ short8 bfragB(const float* lB, int nl, int kb) {
  short8 r;
#pragma unroll
  for (int j = 0; j < 8; ++j) r[j] = (short)f2bf(lB[(kb + j) * 64 + nl]);
  return r;
}

static __device__ __forceinline__ void mma1f(const unsigned short* lA, const float* lB,
    f32x4 (&acc)[4][2], int wm, int wn, int lane) {
  int r16 = lane & 15;
  int kg  = (lane >> 4) * 8;
#pragma unroll
  for (int kk = 0; kk < 2; ++kk) {
    int kb = kk * 32 + kg;
    short8 a[4], b[2];
#pragma unroll
    for (int mf = 0; mf < 4; ++mf) a[mf] = frag_ldA(lA, wm + mf * 16 + r16, kb);
#pragma unroll
    for (int nf = 0; nf < 2; ++nf) b[nf] = bfragB(lB, wn + nf * 16 + r16, kb);
#pragma unroll
    for (int mf = 0; mf < 4; ++mf)
#pragma unroll
      for (int nf = 0; nf < 2; ++nf)
        acc[mf][nf] = __builtin_amdgcn_mfma_f32_16x16x32_bf16(a[mf], b[nf], acc[mf][nf], 0, 0, 0);
  }
}

static __device__ __forceinline__ void mma2f(const unsigned short* lA,
    const float* lBg, const float* lBu,
    f32x4 (&accg)[4][2], f32x4 (&accu)[4][2], int wm, int wn, int lane) {
  int r16 = lane & 15;
  int kg  = (lane >> 4) * 8;
#pragma unroll
  for (int kk = 0; kk < 2; ++kk) {
    int kb = kk * 32 + kg;
    short8 a[4], bg[2], bu[2];
#pragma unroll
    for (int mf = 0; mf < 4; ++mf) a[mf] = frag_ldA(lA, wm + mf * 16 + r16, kb);
#pragma unroll
    for (int nf = 0; nf < 2; ++nf) {
      bg[nf] = bfragB(lBg, wn + nf * 16 + r16, kb);
      bu[nf] = bfragB(lBu, wn + nf * 16 + r16, kb);
    }
#pragma unroll
    for (int mf = 0; mf < 4; ++mf)
#pragma unroll
      for (int nf = 0; nf < 2; ++nf) {
        accg[mf][nf] = __builtin_amdgcn_mfma_f32_16x16x32_bf16(a[mf], bg[nf], accg[mf][nf], 0, 0, 0);
        accu[mf][nf] = __builtin_amdgcn_mfma_f32_16x16x32_bf16(a[mf], bu[nf], accu[mf][nf], 0, 0, 0);
      }
  }
}

static __device__ __forceinline__ float silu_mul(float g, float u) {
  return g / (1.f + expf(-g)) * u;
}

// Per-thread A source pointers for one 128-row tile (4 DMA rounds/wave).
// round p: dest lane l covers row = wv*32 + p*8 + (l>>3), chunk c = l&7.
// Source chunk = c ^ (row&7)  (involutive pre-swizzle).
#define A_SETUP(asrc, SROW_EXPR)                                            \
  const unsigned short* asrc[4];                                            \
  {                                                                         \
    _Pragma("unroll")                                                       \
    for (int p = 0; p < 4; ++p) {                                           \
      int row = wv * 32 + p * 8 + (lane >> 3);                              \
      int srow = (SROW_EXPR);                                               \
      asrc[p] = Abase + (size_t)srow * lda + (((lane & 7) ^ (row & 7)) << 3);\
    }                                                                       \
  }

// B: round p: dest lane l covers k = wv*16 + p*4 + (l>>4), 4-float chunk l&15.
#define B_SETUP(bsrc, Bbase, ldb)                                           \
  const float* bsrc[4];                                                     \
  {                                                                         \
    _Pragma("unroll")                                                       \
    for (int p = 0; p < 4; ++p) {                                           \
      int k = wv * 16 + p * 4 + (lane >> 4);                                \
      bsrc[p] = (Bbase) + (size_t)k * (ldb) + n0 + (lane & 15) * 4;         \
    }                                                                       \
  }

#define A_STAGE(asrc, lA, k0)                                               \
  _Pragma("unroll")                                                         \
  for (int p = 0; p < 4; ++p) GLDS16(asrc[p] + (k0), (lA) + wv * 2048 + p * 512);

#define B_STAGE(bsrc, lB, k0, ldb)                                          \
  _Pragma("unroll")                                                         \
  for (int p = 0; p < 4; ++p) GLDS16(bsrc[p] + (size_t)(k0) * (ldb), (lB) + wv * 1024 + p * 256);

// ---------------------------------------------------------------- expert gate+up
__global__ __launch_bounds__(256, 3) void k_expert_gateup(const unsigned short* __restrict__ xbf,
    const float* __restrict__ Wg, const float* __restrict__ Wu,
    const int* __restrict__ cnt, const int* __restrict__ offs,
    const int* __restrict__ lists, unsigned short* __restrict__ hws) {
  int e = blockIdx.y;
  int ne = min(cnt[e], CAPC);
  if (ne == 0) return;
  int n0 = blockIdx.x * 64;
  const float* Bg = Wg + (size_t)e * DM * HEXP;
  const float* Bu = Wu + (size_t)e * DM * HEXP;
  const int* lst = lists + e * CAPC;
  int base = offs[e];
  __shared__ unsigned short lA[128 * 64];
  __shared__ float lBg[64 * 64];
  __shared__ float lBu[64 * 64];
  int tid = threadIdx.x;
  int lane = tid & 63, wv = tid >> 6;
  int wm = (wv >> 1) * 64, wn = (wv & 1) * 32;
  const unsigned short* Abase = xbf; const int lda = DM;
  B_SETUP(bgsrc, Bg, HEXP)
  B_SETUP(busrc, Bu, HEXP)
  for (int m0 = 0; m0 < ne; m0 += 128) {
    A_SETUP(asrc, lst[min(m0 + row, ne - 1)])
    f32x4 accg[4][2] = {};
    f32x4 accu[4][2] = {};
    for (int k0 = 0; k0 < DM; k0 += 64) {
      A_STAGE(asrc, lA, k0)
      B_STAGE(bgsrc, lBg, k0, HEXP)
      B_STAGE(busrc, lBu, k0, HEXP)
      __syncthreads();
      mma2f(lA, lBg, lBu, accg, accu, wm, wn, lane);
      __syncthreads();
    }
#pragma unroll
    for (int mf = 0; mf < 4; ++mf)
#pragma unroll
      for (int r = 0; r < 4; ++r) {
        int rl = m0 + wm + mf * 16 + (lane >> 4) * 4 + r;
        if (rl < ne) {
#pragma unroll
          for (int nf = 0; nf < 2; ++nf) {
            int col = n0 + wn + nf * 16 + (lane & 15);
            float h = silu_mul(accg[mf][nf][r], accu[mf][nf][r]);
            hws[(size_t)(base + rl) * HEXP + col] = f2bf(h);
          }
        }
      }
  }
}

// ---------------------------------------------------------------- shared gate+up
__global__ __launch_bounds__(256, 3) void k_shared_gateup(const unsigned short* __restrict__ xbf,
    const float* __restrict__ Sg, const float* __restrict__ Su,
    unsigned short* __restrict__ hs) {
  int n0 = blockIdx.x * 64;
  int m0 = blockIdx.y * 128;
  int s  = blockIdx.z;
  const float* Bg = Sg + (size_t)s * DM * HSH;
  const float* Bu = Su + (size_t)s * DM * HSH;
  __shared__ unsigned short lA[128 * 64];
  __shared__ float lBg[64 * 64];
  __shared__ float lBu[64 * 64];
  int tid = threadIdx.x;
  int lane = tid & 63, wv = tid >> 6;
  int wm = (wv >> 1) * 64, wn = (wv & 1) * 32;
  const unsigned short* Abase = xbf; const int lda = DM;
  B_SETUP(bgsrc, Bg, HSH)
  B_SETUP(busrc, Bu, HSH)
  A_SETUP(asrc, m0 + row)
  f32x4 accg[4][2] = {};
  f32x4 accu[4][2] = {};
  for (int k0 = 0; k0 < DM; k0 += 64) {
    A_STAGE(asrc, lA, k0)
    B_STAGE(bgsrc, lBg, k0, HSH)
    B_STAGE(busrc, lBu, k0, HSH)
    __syncthreads();
    mma2f(lA, lBg, lBu, accg, accu, wm, wn, lane);
    __syncthreads();
  }
#pragma unroll
  for (int mf = 0; mf < 4; ++mf)
#pragma unroll
    for (int nf = 0; nf < 2; ++nf)
#pragma unroll
      for (int r = 0; r < 4; ++r) {
        int row = m0 + wm + mf * 16 + (lane >> 4) * 4 + r;
        int col = n0 + wn + nf * 16 + (lane & 15);
        float h = silu_mul(accg[mf][nf][r], accu[mf][nf][r]);
        hs[(size_t)row * (NSH * HSH) + s * HSH + col] = f2bf(h);
      }
}

// ---------------------------------------------------------------- shared down (writes out)
__global__ __launch_bounds__(256, 3) void k_shared_down(const unsigned short* __restrict__ hs,
    const float* __restrict__ Sd, float* __restrict__ out) {
  int n0 = blockIdx.x * 64;
  int m0 = blockIdx.y * 128;
  __shared__ unsigned short lA[128 * 64];
  __shared__ float lB[64 * 64];
  int tid = threadIdx.x;
  int lane = tid & 63, wv = tid >> 6;
  int wm = (wv >> 1) * 64, wn = (wv & 1) * 32;
  const unsigned short* Abase = hs; const int lda = NSH * HSH;
  B_SETUP(bsrc, Sd, DM)
  A_SETUP(asrc, m0 + row)
  f32x4 acc[4][2] = {};
  for (int k0 = 0; k0 < NSH * HSH; k0 += 64) {
    A_STAGE(asrc, lA, k0)
    B_STAGE(bsrc, lB, k0, DM)
    __syncthreads();
    mma1f(lA, lB, acc, wm, wn, lane);
    __syncthreads();
  }
#pragma unroll
  for (int mf = 0; mf < 4; ++mf)
#pragma unroll
    for (int nf = 0; nf < 2; ++nf)
#pragma unroll
      for (int r = 0; r < 4; ++r) {
        int row = m0 + wm + mf * 16 + (lane >> 4) * 4 + r;
        int col = n0 + wn + nf * 16 + (lane & 15);
        out[(size_t)row * DM + col] = acc[mf][nf][r];
      }
}

// ---------------------------------------------------------------- expert down (atomic add)
__global__ __launch_bounds__(256, 3) void k_expert_down(const unsigned short* __restrict__ hws,
    const float* __restrict__ Wd, const int* __restrict__ cnt, const int* __restrict__ offs,
    const int* __restrict__ lists, const float* __restrict__ wlist,
    float* __restrict__ out) {
  int e = blockIdx.y;
  int ne = min(cnt[e], CAPC);
  if (ne == 0) return;
  int n0 = blockIdx.x * 64;
  const float* B = Wd + (size_t)e * HEXP * DM;
  __shared__ unsigned short lA[128 * 64];
  __shared__ float lB[64 * 64];
  int tid = threadIdx.x;
  int lane = tid & 63, wv = tid >> 6;
  int wm = (wv >> 1) * 64, wn = (wv & 1) * 32;
  const unsigned short* Abase = hws + (size_t)offs[e] * HEXP; const int lda = HEXP;
  B_SETUP(bsrc, B, DM)
  for (int m0 = 0; m0 < ne; m0 += 128) {
    A_SETUP(asrc, min(m0 + row, ne - 1))
    f32x4 acc[4][2] = {};
    for (int k0 = 0; k0 < HEXP; k0 += 64) {
      A_STAGE(asrc, lA, k0)
      B_STAGE(bsrc, lB, k0, DM)
      __syncthreads();
      mma1f(lA, lB, acc, wm, wn, lane);
      __syncthreads();
    }
#pragma unroll
    for (int mf = 0; mf < 4; ++mf)
#pragma unroll
      for (int r = 0; r < 4; ++r) {
        int rl = m0 + wm + mf * 16 + (lane >> 4) * 4 + r;
        if (rl < ne) {
          int tok  = lists[e * CAPC + rl];
          float w  = wlist[e * CAPC + rl];
#pragma unroll
          for (int nf = 0; nf < 2; ++nf) {
            int col = n0 + wn + nf * 16 + (lane & 15);
            atomicAdd(out + (size_t)tok * DM + col, acc[mf][nf][r] * w);
          }
        }
      }
  }
}

// ---------------------------------------------------------------- launch
extern "C" void kernel_launch(void* const* d_in, const int* in_sizes, int n_in,
                              void* d_out, int out_size, void* d_ws, size_t ws_size,
                              hipStream_t stream) {
  const float* x    = (const float*)d_in[0];
  const float* Wr   = (const float*)d_in[1];
  const float* bias = (const float*)d_in[2];
  const float* Wg   = (const float*)d_in[3];
  const float* Wu   = (const float*)d_in[4];
  const float* Wd   = (const float*)d_in[5];
  const float* Sg   = (const float*)d_in[6];
  const float* Su   = (const float*)d_in[7];
  const float* Sd   = (const float*)d_in[8];
  float* out = (float*)d_out;
  char* ws = (char*)d_ws;

  const size_t off_cnt   = 0;
  const size_t off_offs  = 256;
  const size_t off_lists = 1024;
  const size_t off_wlist = off_lists + (size_t)NEXP * CAPC * 4;
  const size_t off_xbf   = off_wlist + (size_t)NEXP * CAPC * 4;
  const size_t off_hs    = off_xbf + (size_t)N_TOK * DM * 2;
  const size_t off_h     = off_hs + (size_t)N_TOK * NSH * HSH * 2;
  const size_t req       = off_h + (size_t)N_TOK * TOPK * HEXP * 2;
  if (ws_size < req) return;   // loud failure, no corruption

  int* cnt            = (int*)(ws + off_cnt);
  int* offs           = (int*)(ws + off_offs);
  int* lists          = (int*)(ws + off_lists);
  float* wlist        = (float*)(ws + off_wlist);
  unsigned short* xbf = (unsigned short*)(ws + off_xbf);
  unsigned short* hs  = (unsigned short*)(ws + off_hs);
  unsigned short* hws = (unsigned short*)(ws + off_h);

  hipMemsetAsync(cnt, 0, NEXP * sizeof(int), stream);
  k_convert<<<(N_TOK * DM) / (256 * 8), 256, 0, stream>>>(x, xbf);
  k_router<<<N_TOK / RTB, 256, 0, stream>>>(x, Wr, bias, cnt, lists, wlist);
  k_offs<<<1, 64, 0, stream>>>(cnt, offs);
  k_expert_gateup<<<dim3(HEXP / 64, NEXP), 256, 0, stream>>>(xbf, Wg, Wu, cnt, offs, lists, hws);
  k_shared_gateup<<<dim3(HSH / 64, N_TOK / 128, NSH), 256, 0, stream>>>(xbf, Sg, Su, hs);
  k_shared_down<<<dim3(DM / 64, N_TOK / 128), 256, 0, stream>>>(hs, Sd, out);
  k_expert_down<<<dim3(DM / 64, NEXP), 256, 0, stream>>>(hws, Wd, cnt, offs, lists, wlist, out);
}

// Round 5
// 662.538 us; speedup vs baseline: 1.0894x; 1.0126x over previous
//
#include <hip/hip_runtime.h>
#include <hip/hip_bf16.h>
#include <stdint.h>

#define N_TOK 2048
#define DM    2048
#define NEXP  64
#define TOPK  4
#define HEXP  512
#define CAPC  512
#define NSH   2
#define HSH   2048
#define RTB   8

typedef __attribute__((ext_vector_type(8))) short short8;
typedef __attribute__((ext_vector_type(4))) float f32x4;
typedef __attribute__((ext_vector_type(4))) float f4;
typedef __attribute__((ext_vector_type(4))) unsigned uint4v;

// Direct global->LDS DMA, 16B per lane. LDS dest = wave-uniform base + lane*16.
#define GLDS16(g, l) __builtin_amdgcn_global_load_lds(                     \
    (const __attribute__((address_space(1))) void*)(g),                    \
    (__attribute__((address_space(3))) void*)(l), 16, 0, 0)

// Counted VMEM wait: NEVER 0 inside the k-loop (loads stay in flight).
#define VMWAIT(N) asm volatile("s_waitcnt vmcnt(" #N ")" ::: "memory")
// Raw barrier with compiler-level memory fences on both sides.
#define BARX() do { asm volatile("" ::: "memory");                          \
                    __builtin_amdgcn_s_barrier();                           \
                    asm volatile("" ::: "memory"); } while (0)

static __device__ __forceinline__ unsigned short f2bf(float f) {
  union { float f; unsigned u; } v; v.f = f;
  unsigned r = v.u + 0x7FFFu + ((v.u >> 16) & 1u);   // RNE
  return (unsigned short)(r >> 16);
}

// ---------------------------------------------------------------- convert x
__global__ __launch_bounds__(256) void k_convert(const float* __restrict__ x,
                                                 unsigned short* __restrict__ xb) {
  int i = (blockIdx.x * 256 + threadIdx.x) * 8;
  f4 a = *(const f4*)(x + i);
  f4 b = *(const f4*)(x + i + 4);
  short8 o;
  o[0]=f2bf(a[0]); o[1]=f2bf(a[1]); o[2]=f2bf(a[2]); o[3]=f2bf(a[3]);
  o[4]=f2bf(b[0]); o[5]=f2bf(b[1]); o[6]=f2bf(b[2]); o[7]=f2bf(b[3]);
  *(short8*)(xb + i) = o;
}

// ---------------------------------------------------------------- router
#define ARGMAX_ROUND(S,I)                                            \
  { float bv = v; int bi = lane;                                     \
    _Pragma("unroll")                                                \
    for (int o = 32; o; o >>= 1) {                                   \
      float ov = __shfl_xor(bv, o); int oi = __shfl_xor(bi, o);      \
      if (ov > bv || (ov == bv && oi < bi)) { bv = ov; bi = oi; }    \
    }                                                                \
    S = bv; I = bi; if (lane == bi) v = -1.f; }

__global__ __launch_bounds__(256) void k_router(const float* __restrict__ x,
    const float* __restrict__ Wr, const float* __restrict__ bias,
    int* __restrict__ cnt, int* __restrict__ lists, float* __restrict__ wlist) {
  __shared__ float part[4][RTB][64];
  __shared__ float logits[RTB][64];
  int t = threadIdx.x;
  int e = t & 63, sl = t >> 6;
  int tok0 = blockIdx.x * RTB;
  const float* xp = x + (size_t)tok0 * DM;
  float acc[RTB];
#pragma unroll
  for (int i = 0; i < RTB; ++i) acc[i] = 0.f;
  for (int d = sl * 512; d < sl * 512 + 512; ++d) {
    float w = Wr[(size_t)d * NEXP + e];
#pragma unroll
    for (int i = 0; i < RTB; ++i) acc[i] += xp[(size_t)i * DM + d] * w;
  }
#pragma unroll
  for (int i = 0; i < RTB; ++i) part[sl][i][e] = acc[i];
  __syncthreads();
  for (int i = sl; i < RTB; i += 4)
    logits[i][e] = part[0][i][e] + part[1][i][e] + part[2][i][e] + part[3][i][e] + bias[e];
  __syncthreads();
  int lane = t & 63, wv = t >> 6;
  for (int i = wv * 2; i < wv * 2 + 2; ++i) {
    float lg = logits[i][lane];
    float m = lg;
#pragma unroll
    for (int o = 32; o; o >>= 1) m = fmaxf(m, __shfl_xor(m, o));
    float p = expf(lg - m);
    float sm = p;
#pragma unroll
    for (int o = 32; o; o >>= 1) sm += __shfl_xor(sm, o);
    float v = p / sm;
    float s0, s1, s2, s3; int i0, i1, i2, i3;
    ARGMAX_ROUND(s0, i0)
    ARGMAX_ROUND(s1, i1)
    ARGMAX_ROUND(s2, i2)
    ARGMAX_ROUND(s3, i3)
    float tot = s0 + s1 + s2 + s3;
    if (lane < TOPK) {
      float myw = (lane == 0 ? s0 : lane == 1 ? s1 : lane == 2 ? s2 : s3) / tot;
      int   mye = (lane == 0 ? i0 : lane == 1 ? i1 : lane == 2 ? i2 : i3);
      int pos = atomicAdd(&cnt[mye], 1);
      if (pos < CAPC) {
        lists[mye * CAPC + pos] = tok0 + i;
        wlist[mye * CAPC + pos] = myw;
      }
    }
  }
}

// ---------------------------------------------------------------- offsets
__global__ void k_offs(const int* __restrict__ cnt, int* __restrict__ offs) {
  int l = threadIdx.x;            // 64 threads
  int c = min(cnt[l], CAPC);
  int sum = c;
#pragma unroll
  for (int o = 1; o < 64; o <<= 1) {
    int ov = __shfl_up(sum, o);
    if (l >= o) sum += ov;
  }
  offs[l + 1] = sum;
  if (l == 0) offs[0] = 0;
}

// ---------------------------------------------------------------- GEMM pieces
// BK=32. A LDS: [128 r][32 k] bf16 (64B rows), DMA-linear; source chunk (16B)
// pre-permuted c^=((row>>1)&3), read XOR byte^=((row>>1)&3)<<4  -> 2-way max.
// B LDS: [32 k][64 n] fp32 (256B rows), DMA-linear; source 4-float chunk
// pre-permuted c^=((k>>3)&1)<<2, read word = k*64 + (n ^ ((k>>3)&1)<<4).

static __device__ __forceinline__ short8 frag_ldA(const unsigned short* lds, int row, int kElem) {
  int byte = row * 64 + kElem * 2;
  byte ^= ((row >> 1) & 3) << 4;
  return *(const short8*)((const char*)lds + byte);
}

static __device__ __forceinline__ short8 bfragB(const float* lB, int nl, int kb) {
  const float* p = lB + kb * 64 + (nl ^ (((kb >> 3) & 1) << 4));
  float f0 = p[0],   f1 = p[64],  f2 = p[128], f3 = p[192];
  float f4_ = p[256], f5 = p[320], f6 = p[384], f7 = p[448];
  unsigned u0, u1, u2, u3;
  asm("v_cvt_pk_bf16_f32 %0, %1, %2" : "=v"(u0) : "v"(f0),  "v"(f1));
  asm("v_cvt_pk_bf16_f32 %0, %1, %2" : "=v"(u1) : "v"(f2),  "v"(f3));
  asm("v_cvt_pk_bf16_f32 %0, %1, %2" : "=v"(u2) : "v"(f4_), "v"(f5));
  asm("v_cvt_pk_bf16_f32 %0, %1, %2" : "=v"(u3) : "v"(f6),  "v"(f7));
  uint4v uv = {u0, u1, u2, u3};
  return __builtin_bit_cast(short8, uv);
}

static __device__ __forceinline__ void mma1f(const unsigned short* lA, const float* lB,
    f32x4 (&acc)[4][2], int wm, int wn, int lane) {
  int r16 = lane & 15;
  int kb  = (lane >> 4) * 8;
  short8 a[4], b[2];
#pragma unroll
  for (int mf = 0; mf < 4; ++mf) a[mf] = frag_ldA(lA, wm + mf * 16 + r16, kb);
#pragma unroll
  for (int nf = 0; nf < 2; ++nf) b[nf] = bfragB(lB, wn + nf * 16 + r16, kb);
#pragma unroll
  for (int mf = 0; mf < 4; ++mf)
#pragma unroll
    for (int nf = 0; nf < 2; ++nf)
      acc[mf][nf] = __builtin_amdgcn_mfma_f32_16x16x32_bf16(a[mf], b[nf], acc[mf][nf], 0, 0, 0);
}

static __device__ __forceinline__ void mma2f(const unsigned short* lA,
    const float* lBg, const float* lBu,
    f32x4 (&accg)[4][2], f32x4 (&accu)[4][2], int wm, int wn, int lane) {
  int r16 = lane & 15;
  int kb  = (lane >> 4) * 8;
  short8 a[4], bg[2], bu[2];
#pragma unroll
  for (int mf = 0; mf < 4; ++mf) a[mf] = frag_ldA(lA, wm + mf * 16 + r16, kb);
#pragma unroll
  for (int nf = 0; nf < 2; ++nf) {
    bg[nf] = bfragB(lBg, wn + nf * 16 + r16, kb);
    bu[nf] = bfragB(lBu, wn + nf * 16 + r16, kb);
  }
#pragma unroll
  for (int mf = 0; mf < 4; ++mf)
#pragma unroll
    for (int nf = 0; nf < 2; ++nf) {
      accg[mf][nf] = __builtin_amdgcn_mfma_f32_16x16x32_bf16(a[mf], bg[nf], accg[mf][nf], 0, 0, 0);
      accu[mf][nf] = __builtin_amdgcn_mfma_f32_16x16x32_bf16(a[mf], bu[nf], accu[mf][nf], 0, 0, 0);
    }
}

static __device__ __forceinline__ float silu_mul(float g, float u) {
  return g / (1.f + expf(-g)) * u;
}

// A: 2 DMA rounds/wave/tile. Round p: row = p*64 + wv*16 + (lane>>2), chunk lane&3.
#define A_SETUP(asrc, SROW_EXPR)                                            \
  const unsigned short* asrc[2];                                            \
  {                                                                         \
    _Pragma("unroll")                                                       \
    for (int p = 0; p < 2; ++p) {                                           \
      int row = p * 64 + wv * 16 + (lane >> 2);                             \
      int srow = (SROW_EXPR);                                               \
      asrc[p] = Abase + (size_t)srow * lda                                  \
              + (((lane & 3) ^ ((row >> 1) & 3)) << 3);                     \
    }                                                                       \
  }
#define A_STAGE(asrc, lAbuf, k0)                                            \
  { _Pragma("unroll")                                                       \
    for (int p = 0; p < 2; ++p)                                             \
      GLDS16(asrc[p] + (k0), (lAbuf) + p * 2048 + wv * 512); }

// B: 2 DMA rounds/wave/tile. Round p: k = p*16 + wv*4 + (lane>>4), chunk lane&15.
#define B_SETUP(bsrc, Bbase, ldb)                                           \
  const float* bsrc[2];                                                     \
  {                                                                         \
    _Pragma("unroll")                                                       \
    for (int p = 0; p < 2; ++p) {                                           \
      int k = p * 16 + wv * 4 + (lane >> 4);                                \
      int c = (lane & 15) ^ (((k >> 3) & 1) << 2);                          \
      bsrc[p] = (Bbase) + (size_t)k * (ldb) + n0 + c * 4;                   \
    }                                                                       \
  }
#define B_STAGE(bsrc, lBbuf, k0, ldb)                                       \
  { _Pragma("unroll")                                                       \
    for (int p = 0; p < 2; ++p)                                             \
      GLDS16(bsrc[p] + (size_t)(k0) * (ldb), (lBbuf) + p * 1024 + wv * 256); }

// ---------------------------------------------------------------- expert gate+up
__global__ __launch_bounds__(256, 3) void k_expert_gateup(const unsigned short* __restrict__ xbf,
    const float* __restrict__ Wg, const float* __restrict__ Wu,
    const int* __restrict__ cnt, const int* __restrict__ offs,
    const int* __restrict__ lists, unsigned short* __restrict__ hws) {
  int e = blockIdx.y;
  int ne = min(cnt[e], CAPC);
  if (ne == 0) return;
  int n0 = blockIdx.x * 64;
  const float* Bg = Wg + (size_t)e * DM * HEXP;
  const float* Bu = Wu + (size_t)e * DM * HEXP;
  const int* lst = lists + e * CAPC;
  int base = offs[e];
  __shared__ unsigned short lA[2][128 * 32];
  __shared__ float lBg[2][32 * 64];
  __shared__ float lBu[2][32 * 64];
  int tid = threadIdx.x;
  int lane = tid & 63, wv = tid >> 6;
  int wm = (wv >> 1) * 64, wn = (wv & 1) * 32;
  const unsigned short* Abase = xbf; const int lda = DM;
  B_SETUP(bgsrc, Bg, HEXP)
  B_SETUP(busrc, Bu, HEXP)
  const int NT = DM / 32;           // 64
  for (int m0 = 0; m0 < ne; m0 += 128) {
    A_SETUP(asrc, lst[min(m0 + row, ne - 1)])
    f32x4 accg[4][2] = {};
    f32x4 accu[4][2] = {};
    A_STAGE(asrc, lA[0], 0)  B_STAGE(bgsrc, lBg[0], 0, HEXP)  B_STAGE(busrc, lBu[0], 0, HEXP)
    A_STAGE(asrc, lA[1], 32) B_STAGE(bgsrc, lBg[1], 32, HEXP) B_STAGE(busrc, lBu[1], 32, HEXP)
    VMWAIT(6); BARX();
#pragma unroll 1
    for (int t = 0; t < NT; t += 2) {
      mma2f(lA[0], lBg[0], lBu[0], accg, accu, wm, wn, lane);
      BARX();
      if (t + 2 < NT) {
        int k2 = (t + 2) * 32;
        A_STAGE(asrc, lA[0], k2) B_STAGE(bgsrc, lBg[0], k2, HEXP) B_STAGE(busrc, lBu[0], k2, HEXP)
        VMWAIT(6);
      } else { VMWAIT(0); }
      BARX();
      mma2f(lA[1], lBg[1], lBu[1], accg, accu, wm, wn, lane);
      if (t + 2 < NT) {
        BARX();
        if (t + 3 < NT) {
          int k3 = (t + 3) * 32;
          A_STAGE(asrc, lA[1], k3) B_STAGE(bgsrc, lBg[1], k3, HEXP) B_STAGE(busrc, lBu[1], k3, HEXP)
          VMWAIT(6);
        } else { VMWAIT(0); }
        BARX();
      }
    }
    BARX();   // protect LDS reuse across m0 iterations
#pragma unroll
    for (int mf = 0; mf < 4; ++mf)
#pragma unroll
      for (int r = 0; r < 4; ++r) {
        int rl = m0 + wm + mf * 16 + (lane >> 4) * 4 + r;
        if (rl < ne) {
#pragma unroll
          for (int nf = 0; nf < 2; ++nf) {
            int col = n0 + wn + nf * 16 + (lane & 15);
            float h = silu_mul(accg[mf][nf][r], accu[mf][nf][r]);
            hws[(size_t)(base + rl) * HEXP + col] = f2bf(h);
          }
        }
      }
  }
}

// ---------------------------------------------------------------- shared gate+up
__global__ __launch_bounds__(256, 3) void k_shared_gateup(const unsigned short* __restrict__ xbf,
    const float* __restrict__ Sg, const float* __restrict__ Su,
    unsigned short* __restrict__ hs) {
  int n0 = blockIdx.x * 64;
  int m0 = blockIdx.y * 128;
  int s  = blockIdx.z;
  const float* Bg = Sg + (size_t)s * DM * HSH;
  const float* Bu = Su + (size_t)s * DM * HSH;
  __shared__ unsigned short lA[2][128 * 32];
  __shared__ float lBg[2][32 * 64];
  __shared__ float lBu[2][32 * 64];
  int tid = threadIdx.x;
  int lane = tid & 63, wv = tid >> 6;
  int wm = (wv >> 1) * 64, wn = (wv & 1) * 32;
  const unsigned short* Abase = xbf; const int lda = DM;
  B_SETUP(bgsrc, Bg, HSH)
  B_SETUP(busrc, Bu, HSH)
  A_SETUP(asrc, m0 + row)
  f32x4 accg[4][2] = {};
  f32x4 accu[4][2] = {};
  const int NT = DM / 32;           // 64
  A_STAGE(asrc, lA[0], 0)  B_STAGE(bgsrc, lBg[0], 0, HSH)  B_STAGE(busrc, lBu[0], 0, HSH)
  A_STAGE(asrc, lA[1], 32) B_STAGE(bgsrc, lBg[1], 32, HSH) B_STAGE(busrc, lBu[1], 32, HSH)
  VMWAIT(6); BARX();
#pragma unroll 1
  for (int t = 0; t < NT; t += 2) {
    mma2f(lA[0], lBg[0], lBu[0], accg, accu, wm, wn, lane);
    BARX();
    if (t + 2 < NT) {
      int k2 = (t + 2) * 32;
      A_STAGE(asrc, lA[0], k2) B_STAGE(bgsrc, lBg[0], k2, HSH) B_STAGE(busrc, lBu[0], k2, HSH)
      VMWAIT(6);
    } else { VMWAIT(0); }
    BARX();
    mma2f(lA[1], lBg[1], lBu[1], accg, accu, wm, wn, lane);
    if (t + 2 < NT) {
      BARX();
      if (t + 3 < NT) {
        int k3 = (t + 3) * 32;
        A_STAGE(asrc, lA[1], k3) B_STAGE(bgsrc, lBg[1], k3, HSH) B_STAGE(busrc, lBu[1], k3, HSH)
        VMWAIT(6);
      } else { VMWAIT(0); }
      BARX();
    }
  }
#pragma unroll
  for (int mf = 0; mf < 4; ++mf)
#pragma unroll
    for (int nf = 0; nf < 2; ++nf)
#pragma unroll
      for (int r = 0; r < 4; ++r) {
        int row = m0 + wm + mf * 16 + (lane >> 4) * 4 + r;
        int col = n0 + wn + nf * 16 + (lane & 15);
        float h = silu_mul(accg[mf][nf][r], accu[mf][nf][r]);
        hs[(size_t)row * (NSH * HSH) + s * HSH + col] = f2bf(h);
      }
}

// ---------------------------------------------------------------- shared down (writes out)
__global__ __launch_bounds__(256, 4) void k_shared_down(const unsigned short* __restrict__ hs,
    const float* __restrict__ Sd, float* __restrict__ out) {
  int n0 = blockIdx.x * 64;
  int m0 = blockIdx.y * 128;
  __shared__ unsigned short lA[2][128 * 32];
  __shared__ float lB[2][32 * 64];
  int tid = threadIdx.x;
  int lane = tid & 63, wv = tid >> 6;
  int wm = (wv >> 1) * 64, wn = (wv & 1) * 32;
  const unsigned short* Abase = hs; const int lda = NSH * HSH;
  B_SETUP(bsrc, Sd, DM)
  A_SETUP(asrc, m0 + row)
  f32x4 acc[4][2] = {};
  const int NT = (NSH * HSH) / 32;  // 128
  A_STAGE(asrc, lA[0], 0)  B_STAGE(bsrc, lB[0], 0, DM)
  A_STAGE(asrc, lA[1], 32) B_STAGE(bsrc, lB[1], 32, DM)
  VMWAIT(4); BARX();
#pragma unroll 1
  for (int t = 0; t < NT; t += 2) {
    mma1f(lA[0], lB[0], acc, wm, wn, lane);
    BARX();
    if (t + 2 < NT) {
      int k2 = (t + 2) * 32;
      A_STAGE(asrc, lA[0], k2) B_STAGE(bsrc, lB[0], k2, DM)
      VMWAIT(4);
    } else { VMWAIT(0); }
    BARX();
    mma1f(lA[1], lB[1], acc, wm, wn, lane);
    if (t + 2 < NT) {
      BARX();
      if (t + 3 < NT) {
        int k3 = (t + 3) * 32;
        A_STAGE(asrc, lA[1], k3) B_STAGE(bsrc, lB[1], k3, DM)
        VMWAIT(4);
      } else { VMWAIT(0); }
      BARX();
    }
  }
#pragma unroll
  for (int mf = 0; mf < 4; ++mf)
#pragma unroll
    for (int nf = 0; nf < 2; ++nf)
#pragma unroll
      for (int r = 0; r < 4; ++r) {
        int row = m0 + wm + mf * 16 + (lane >> 4) * 4 + r;
        int col = n0 + wn + nf * 16 + (lane & 15);
        out[(size_t)row * DM + col] = acc[mf][nf][r];
      }
}

// ---------------------------------------------------------------- expert down (atomic add)
__global__ __launch_bounds__(256, 4) void k_expert_down(const unsigned short* __restrict__ hws,
    const float* __restrict__ Wd, const int* __restrict__ cnt, const int* __restrict__ offs,
    const int* __restrict__ lists, const float* __restrict__ wlist,
    float* __restrict__ out) {
  int e = blockIdx.y;
  int ne = min(cnt[e], CAPC);
  if (ne == 0) return;
  int n0 = blockIdx.x * 64;
  const float* B = Wd + (size_t)e * HEXP * DM;
  __shared__ unsigned short lA[2][128 * 32];
  __shared__ float lB[2][32 * 64];
  int tid = threadIdx.x;
  int lane = tid & 63, wv = tid >> 6;
  int wm = (wv >> 1) * 64, wn = (wv & 1) * 32;
  const unsigned short* Abase = hws + (size_t)offs[e] * HEXP; const int lda = HEXP;
  B_SETUP(bsrc, B, DM)
  const int NT = HEXP / 32;         // 16
  for (int m0 = 0; m0 < ne; m0 += 128) {
    A_SETUP(asrc, min(m0 + row, ne - 1))
    f32x4 acc[4][2] = {};
    A_STAGE(asrc, lA[0], 0)  B_STAGE(bsrc, lB[0], 0, DM)
    A_STAGE(asrc, lA[1], 32) B_STAGE(bsrc, lB[1], 32, DM)
    VMWAIT(4); BARX();
#pragma unroll 1
    for (int t = 0; t < NT; t += 2) {
      mma1f(lA[0], lB[0], acc, wm, wn, lane);
      BARX();
      if (t + 2 < NT) {
        int k2 = (t + 2) * 32;
        A_STAGE(asrc, lA[0], k2) B_STAGE(bsrc, lB[0], k2, DM)
        VMWAIT(4);
      } else { VMWAIT(0); }
      BARX();
      mma1f(lA[1], lB[1], acc, wm, wn, lane);
      if (t + 2 < NT) {
        BARX();
        if (t + 3 < NT) {
          int k3 = (t + 3) * 32;
          A_STAGE(asrc, lA[1], k3) B_STAGE(bsrc, lB[1], k3, DM)
          VMWAIT(4);
        } else { VMWAIT(0); }
        BARX();
      }
    }
    BARX();   // protect LDS reuse across m0 iterations
#pragma unroll
    for (int mf = 0; mf < 4; ++mf)
#pragma unroll
      for (int r = 0; r < 4; ++r) {
        int rl = m0 + wm + mf * 16 + (lane >> 4) * 4 + r;
        if (rl < ne) {
          int tok  = lists[e * CAPC + rl];
          float w  = wlist[e * CAPC + rl];
#pragma unroll
          for (int nf = 0; nf < 2; ++nf) {
            int col = n0 + wn + nf * 16 + (lane & 15);
            atomicAdd(out + (size_t)tok * DM + col, acc[mf][nf][r] * w);
          }
        }
      }
  }
}

// ---------------------------------------------------------------- launch
extern "C" void kernel_launch(void* const* d_in, const int* in_sizes, int n_in,
                              void* d_out, int out_size, void* d_ws, size_t ws_size,
                              hipStream_t stream) {
  const float* x    = (const float*)d_in[0];
  const float* Wr   = (const float*)d_in[1];
  const float* bias = (const float*)d_in[2];
  const float* Wg   = (const float*)d_in[3];
  const float* Wu   = (const float*)d_in[4];
  const float* Wd   = (const float*)d_in[5];
  const float* Sg   = (const float*)d_in[6];
  const float* Su   = (const float*)d_in[7];
  const float* Sd   = (const float*)d_in[8];
  float* out = (float*)d_out;
  char* ws = (char*)d_ws;

  const size_t off_cnt   = 0;
  const size_t off_offs  = 256;
  const size_t off_lists = 1024;
  const size_t off_wlist = off_lists + (size_t)NEXP * CAPC * 4;
  const size_t off_xbf   = off_wlist + (size_t)NEXP * CAPC * 4;
  const size_t off_hs    = off_xbf + (size_t)N_TOK * DM * 2;
  const size_t off_h     = off_hs + (size_t)N_TOK * NSH * HSH * 2;
  const size_t req       = off_h + (size_t)N_TOK * TOPK * HEXP * 2;
  if (ws_size < req) return;   // loud failure, no corruption

  int* cnt            = (int*)(ws + off_cnt);
  int* offs           = (int*)(ws + off_offs);
  int* lists          = (int*)(ws + off_lists);
  float* wlist        = (float*)(ws + off_wlist);
  unsigned short* xbf = (unsigned short*)(ws + off_xbf);
  unsigned short* hs  = (unsigned short*)(ws + off_hs);
  unsigned short* hws = (unsigned short*)(ws + off_h);

  hipMemsetAsync(cnt, 0, NEXP * sizeof(int), stream);
  k_convert<<<(N_TOK * DM) / (256 * 8), 256, 0, stream>>>(x, xbf);
  k_router<<<N_TOK / RTB, 256, 0, stream>>>(x, Wr, bias, cnt, lists, wlist);
  k_offs<<<1, 64, 0, stream>>>(cnt, offs);
  k_expert_gateup<<<dim3(HEXP / 64, NEXP), 256, 0, stream>>>(xbf, Wg, Wu, cnt, offs, lists, hws);
  k_shared_gateup<<<dim3(HSH / 64, N_TOK / 128, NSH), 256, 0, stream>>>(xbf, Sg, Su, hs);
  k_shared_down<<<dim3(DM / 64, N_TOK / 128), 256, 0, stream>>>(hs, Sd, out);
  k_expert_down<<<dim3(DM / 64, NEXP), 256, 0, stream>>>(hws, Wd, cnt, offs, lists, wlist, out);
}